// Round 1
// baseline (428.919 us; speedup 1.0000x reference)
//
#include <hip/hip_runtime.h>
#include <hip/hip_bf16.h>
#include <math.h>

// Problem: bs=8, seq=2048, d_in=d_out=2048, R=8, ctr_out=32, ctr_final=4
// ws layout (floats): A[8*8*2048] | B[8*8*2048] | xa[8*2048*8]  = 1.5 MB

#define BS 8
#define SEQ 2048
#define DIM 2048
#define RR 8
#define SCALING 2.0f   // 16.0 / R

// ---------------------------------------------------------------------------
// Kernel 1: gating MLP (recomputed per block, cheap) + A/B generation.
// A[b][rd] = sum_c gate[b][c]*Wa[rd][c];  B[b][rd] = SCALING * gate·Wb[rd]
// ---------------------------------------------------------------------------
__global__ void gate_ab_kernel(const float* __restrict__ ctr,
                               const float* __restrict__ gamma,
                               const float* __restrict__ beta,
                               const float* __restrict__ W1,
                               const float* __restrict__ b1,
                               const float* __restrict__ W2,
                               const float* __restrict__ b2,
                               const float* __restrict__ Wa,
                               const float* __restrict__ Wb,
                               float* __restrict__ A,
                               float* __restrict__ B) {
    __shared__ float z_s[BS][32];
    __shared__ float h_s[BS][60];
    __shared__ float logit_s[BS][4];
    __shared__ float gate_s[BS][4];
    const int tid = threadIdx.x;

    // LayerNorm over 32 dims: each 32-thread group = one sample.
    {
        const int b = tid >> 5, i = tid & 31;
        float v = ctr[b * 32 + i];
        float s = v;
        #pragma unroll
        for (int m = 16; m; m >>= 1) s += __shfl_xor(s, m, 64);
        const float mu = s * (1.0f / 32.0f);
        const float d = v - mu;
        float sq = d * d;
        #pragma unroll
        for (int m = 16; m; m >>= 1) sq += __shfl_xor(sq, m, 64);
        const float var = sq * (1.0f / 32.0f);
        z_s[b][i] = d * rsqrtf(var + 1e-5f) * gamma[i] + beta[i];
    }
    __syncthreads();

    // h = relu(z @ W1.T + b1), 8*60 outputs
    for (int idx = tid; idx < BS * 60; idx += 256) {
        const int b = idx / 60, j = idx % 60;
        float acc = b1[j];
        #pragma unroll
        for (int k = 0; k < 32; ++k) acc += z_s[b][k] * W1[j * 32 + k];
        h_s[b][j] = fmaxf(acc, 0.0f);
    }
    __syncthreads();

    // logits = h @ W2.T + b2, 8*4 outputs
    if (tid < 32) {
        const int b = tid >> 2, c = tid & 3;
        float acc = b2[c];
        for (int k = 0; k < 60; ++k) acc += h_s[b][k] * W2[c * 60 + k];
        logit_s[b][c] = acc;
    }
    __syncthreads();

    // softmax over 4
    if (tid < 8) {
        float m = logit_s[tid][0];
        #pragma unroll
        for (int c = 1; c < 4; ++c) m = fmaxf(m, logit_s[tid][c]);
        float e[4], s = 0.0f;
        #pragma unroll
        for (int c = 0; c < 4; ++c) { e[c] = expf(logit_s[tid][c] - m); s += e[c]; }
        const float inv = 1.0f / s;
        #pragma unroll
        for (int c = 0; c < 4; ++c) gate_s[tid][c] = e[c] * inv;
    }
    __syncthreads();

    // A and B: 8 * 16384 elements each; Wa/Wb rows are float4 (4 experts).
    const float4* __restrict__ Wa4 = (const float4*)Wa;
    const float4* __restrict__ Wb4 = (const float4*)Wb;
    const int total = BS * RR * DIM;   // 131072
    for (int idx = blockIdx.x * 256 + tid; idx < total; idx += gridDim.x * 256) {
        const int b = idx >> 14, rd = idx & 16383;
        const float4 g = *(const float4*)gate_s[b];
        const float4 wa = Wa4[rd];
        A[idx] = g.x * wa.x + g.y * wa.y + g.z * wa.z + g.w * wa.w;
        const float4 wb = Wb4[rd];
        B[idx] = SCALING * (g.x * wb.x + g.y * wb.y + g.z * wb.z + g.w * wb.w);
    }
}

// ---------------------------------------------------------------------------
// Kernel 2: xa[b,s,r] = dot(x[b,s,:], A[b,r,:]).  A[b] (64 KB) in LDS.
// 512 blocks (b * 64 tiles of 32 rows), 2 blocks/CU. Each wave register-
// blocks 4 rows so every LDS A-fragment read amortizes over 4 x-rows.
// ---------------------------------------------------------------------------
__global__ void __launch_bounds__(256, 2)
xa_kernel(const float* __restrict__ x, const float* __restrict__ A,
          float* __restrict__ xa) {
    __shared__ float As[RR * DIM];   // 64 KB
    const int b = blockIdx.x >> 6;
    const int tile = blockIdx.x & 63;
    {
        const float4* __restrict__ Ab4 = (const float4*)(A + b * (RR * DIM));
        float4* As4 = (float4*)As;
        for (int i = threadIdx.x; i < RR * DIM / 4; i += 256) As4[i] = Ab4[i];
    }
    __syncthreads();

    const int wave = threadIdx.x >> 6, lane = threadIdx.x & 63;
    const float* __restrict__ xb = x + (size_t)b * SEQ * DIM;
    const int row_base = tile * 32;

    for (int rg = 0; rg < 2; ++rg) {
        const int row = row_base + rg * 16 + wave * 4;
        float acc[4][8];
        #pragma unroll
        for (int i = 0; i < 4; ++i)
            #pragma unroll
            for (int r = 0; r < 8; ++r) acc[i][r] = 0.0f;

        for (int j = 0; j < 8; ++j) {
            const int d = j * 256 + lane * 4;
            float4 a4[8];
            #pragma unroll
            for (int r = 0; r < 8; ++r) a4[r] = *(const float4*)&As[r * DIM + d];
            #pragma unroll
            for (int i = 0; i < 4; ++i) {
                const float4 x4 = *(const float4*)&xb[(size_t)(row + i) * DIM + d];
                #pragma unroll
                for (int r = 0; r < 8; ++r)
                    acc[i][r] += x4.x * a4[r].x + x4.y * a4[r].y +
                                 x4.z * a4[r].z + x4.w * a4[r].w;
            }
        }
        // 64-lane reduction, lane 0 writes
        #pragma unroll
        for (int i = 0; i < 4; ++i) {
            #pragma unroll
            for (int r = 0; r < 8; ++r) {
                float v = acc[i][r];
                #pragma unroll
                for (int off = 32; off; off >>= 1) v += __shfl_down(v, off, 64);
                if (lane == 0) xa[((size_t)b * SEQ + row + i) * RR + r] = v;
            }
        }
    }
}

// ---------------------------------------------------------------------------
// Kernel 3: out[b,s,o] = sum_r xa[b,s,r] * B[b,r,o]   (scaling folded into B)
// Mirror of kernel 2: B[b] in LDS, coalesced float4 stores.
// ---------------------------------------------------------------------------
__global__ void __launch_bounds__(256, 2)
out_kernel(const float* __restrict__ xa, const float* __restrict__ B,
           float* __restrict__ out) {
    __shared__ float Bs[RR * DIM];   // 64 KB
    const int b = blockIdx.x >> 6;
    const int tile = blockIdx.x & 63;
    {
        const float4* __restrict__ Bb4 = (const float4*)(B + b * (RR * DIM));
        float4* Bs4 = (float4*)Bs;
        for (int i = threadIdx.x; i < RR * DIM / 4; i += 256) Bs4[i] = Bb4[i];
    }
    __syncthreads();

    const int wave = threadIdx.x >> 6, lane = threadIdx.x & 63;
    float* __restrict__ ob = out + (size_t)b * SEQ * DIM;
    const float* __restrict__ xab = xa + (size_t)b * SEQ * RR;
    const int row_base = tile * 32;

    for (int rg = 0; rg < 2; ++rg) {
        const int row = row_base + rg * 16 + wave * 4;
        float xv[4][8];
        #pragma unroll
        for (int i = 0; i < 4; ++i) {
            const float4 u0 = *(const float4*)&xab[(size_t)(row + i) * RR];
            const float4 u1 = *(const float4*)&xab[(size_t)(row + i) * RR + 4];
            xv[i][0] = u0.x; xv[i][1] = u0.y; xv[i][2] = u0.z; xv[i][3] = u0.w;
            xv[i][4] = u1.x; xv[i][5] = u1.y; xv[i][6] = u1.z; xv[i][7] = u1.w;
        }
        for (int j = 0; j < 8; ++j) {
            const int o = j * 256 + lane * 4;
            float4 b4[8];
            #pragma unroll
            for (int r = 0; r < 8; ++r) b4[r] = *(const float4*)&Bs[r * DIM + o];
            #pragma unroll
            for (int i = 0; i < 4; ++i) {
                float4 acc = {0.0f, 0.0f, 0.0f, 0.0f};
                #pragma unroll
                for (int r = 0; r < 8; ++r) {
                    acc.x += xv[i][r] * b4[r].x;
                    acc.y += xv[i][r] * b4[r].y;
                    acc.z += xv[i][r] * b4[r].z;
                    acc.w += xv[i][r] * b4[r].w;
                }
                *(float4*)&ob[(size_t)(row + i) * DIM + o] = acc;
            }
        }
    }
}

extern "C" void kernel_launch(void* const* d_in, const int* in_sizes, int n_in,
                              void* d_out, int out_size, void* d_ws, size_t ws_size,
                              hipStream_t stream) {
    const float* x     = (const float*)d_in[0];
    const float* ctr   = (const float*)d_in[1];
    const float* gamma = (const float*)d_in[2];
    const float* beta  = (const float*)d_in[3];
    const float* W1    = (const float*)d_in[4];
    const float* b1    = (const float*)d_in[5];
    const float* W2    = (const float*)d_in[6];
    const float* b2    = (const float*)d_in[7];
    const float* Wa    = (const float*)d_in[8];
    const float* Wb    = (const float*)d_in[9];

    float* ws = (float*)d_ws;
    float* A  = ws;                  // 131072 floats
    float* B  = ws + 131072;         // 131072 floats
    float* xa = ws + 262144;         // 131072 floats
    float* out = (float*)d_out;

    gate_ab_kernel<<<128, 256, 0, stream>>>(ctr, gamma, beta, W1, b1, W2, b2,
                                            Wa, Wb, A, B);
    xa_kernel<<<BS * 64, 256, 0, stream>>>(x, A, xa);
    out_kernel<<<BS * 64, 256, 0, stream>>>(xa, B, out);
}

// Round 2
// 259.027 us; speedup vs baseline: 1.6559x; 1.6559x over previous
//
#include <hip/hip_runtime.h>
#include <hip/hip_bf16.h>
#include <math.h>

// Problem: bs=8, seq=2048, d_in=d_out=2048, R=8, ctr_out=32, ctr_final=4
// ws layout (floats): A[8*8*2048] | B[8*8*2048]  (B has SCALING folded in)

#define BS 8
#define SEQ 2048
#define DIM 2048
#define RR 8
#define SCALING 2.0f   // 16.0 / R

// ---------------------------------------------------------------------------
// Kernel 1: gating MLP (recomputed per block, cheap) + A/B generation.
// ---------------------------------------------------------------------------
__global__ void gate_ab_kernel(const float* __restrict__ ctr,
                               const float* __restrict__ gamma,
                               const float* __restrict__ beta,
                               const float* __restrict__ W1,
                               const float* __restrict__ b1,
                               const float* __restrict__ W2,
                               const float* __restrict__ b2,
                               const float* __restrict__ Wa,
                               const float* __restrict__ Wb,
                               float* __restrict__ A,
                               float* __restrict__ B) {
    __shared__ float z_s[BS][32];
    __shared__ float h_s[BS][60];
    __shared__ float logit_s[BS][4];
    __shared__ float gate_s[BS][4];
    const int tid = threadIdx.x;

    {
        const int b = tid >> 5, i = tid & 31;
        float v = ctr[b * 32 + i];
        float s = v;
        #pragma unroll
        for (int m = 16; m; m >>= 1) s += __shfl_xor(s, m, 64);
        const float mu = s * (1.0f / 32.0f);
        const float d = v - mu;
        float sq = d * d;
        #pragma unroll
        for (int m = 16; m; m >>= 1) sq += __shfl_xor(sq, m, 64);
        const float var = sq * (1.0f / 32.0f);
        z_s[b][i] = d * rsqrtf(var + 1e-5f) * gamma[i] + beta[i];
    }
    __syncthreads();

    for (int idx = tid; idx < BS * 60; idx += 256) {
        const int b = idx / 60, j = idx % 60;
        float acc = b1[j];
        #pragma unroll
        for (int k = 0; k < 32; ++k) acc += z_s[b][k] * W1[j * 32 + k];
        h_s[b][j] = fmaxf(acc, 0.0f);
    }
    __syncthreads();

    if (tid < 32) {
        const int b = tid >> 2, c = tid & 3;
        float acc = b2[c];
        for (int k = 0; k < 60; ++k) acc += h_s[b][k] * W2[c * 60 + k];
        logit_s[b][c] = acc;
    }
    __syncthreads();

    if (tid < 8) {
        float m = logit_s[tid][0];
        #pragma unroll
        for (int c = 1; c < 4; ++c) m = fmaxf(m, logit_s[tid][c]);
        float e[4], s = 0.0f;
        #pragma unroll
        for (int c = 0; c < 4; ++c) { e[c] = expf(logit_s[tid][c] - m); s += e[c]; }
        const float inv = 1.0f / s;
        #pragma unroll
        for (int c = 0; c < 4; ++c) gate_s[tid][c] = e[c] * inv;
    }
    __syncthreads();

    const float4* __restrict__ Wa4 = (const float4*)Wa;
    const float4* __restrict__ Wb4 = (const float4*)Wb;
    const int total = BS * RR * DIM;   // 131072
    for (int idx = blockIdx.x * 256 + tid; idx < total; idx += gridDim.x * 256) {
        const int b = idx >> 14, rd = idx & 16383;
        const float4 g = *(const float4*)gate_s[b];
        const float4 wa = Wa4[rd];
        A[idx] = g.x * wa.x + g.y * wa.y + g.z * wa.z + g.w * wa.w;
        const float4 wb = Wb4[rd];
        B[idx] = SCALING * (g.x * wb.x + g.y * wb.y + g.z * wb.z + g.w * wb.w);
    }
}

// ---------------------------------------------------------------------------
// Fused kernel: per block (b, tile of 32 seq rows):
//   phase 1: stage A[b] in LDS, xa[row][r] = dot(x[row], A[r]) (kept in regs,
//            butterfly-reduced so all lanes hold the sums)
//   phase 2: re-stage same LDS buffer with B[b], out[row] = xa[row]·B
// 512-thread blocks, 64 KB LDS -> 2 blocks/CU, 16 waves/CU (4/SIMD).
// Manual 1-deep load pipeline keeps 8 global loads in flight per wave.
// ---------------------------------------------------------------------------
__global__ void __launch_bounds__(512, 4)
fused_kernel(const float* __restrict__ x, const float* __restrict__ A,
             const float* __restrict__ B, float* __restrict__ out) {
    __shared__ float Ts[RR * DIM];   // 64 KB, reused for A then B
    const int b = blockIdx.x >> 6;
    const int tile = blockIdx.x & 63;
    const int wave = threadIdx.x >> 6, lane = threadIdx.x & 63;

    // ---- stage A[b] ----
    {
        const float4* __restrict__ src = (const float4*)(A + b * (RR * DIM));
        float4* dst = (float4*)Ts;
        for (int i = threadIdx.x; i < RR * DIM / 4; i += 512) dst[i] = src[i];
    }
    __syncthreads();

    const float* __restrict__ xr =
        x + ((size_t)b * SEQ + tile * 32 + wave * 4) * DIM;

    float acc[4][8];
    #pragma unroll
    for (int i = 0; i < 4; ++i)
        #pragma unroll
        for (int r = 0; r < 8; ++r) acc[i][r] = 0.0f;

    // ---- phase 1: xa = x . A^T, pipelined ----
    float4 xcur[4], xnxt[4];
    {
        const int d0 = lane * 4;
        #pragma unroll
        for (int i = 0; i < 4; ++i)
            xcur[i] = *(const float4*)&xr[(size_t)i * DIM + d0];
    }
    #pragma unroll
    for (int j = 0; j < 8; ++j) {
        const int d = j * 256 + lane * 4;
        if (j < 7) {
            #pragma unroll
            for (int i = 0; i < 4; ++i)
                xnxt[i] = *(const float4*)&xr[(size_t)i * DIM + d + 256];
        }
        float4 a4[8];
        #pragma unroll
        for (int r = 0; r < 8; ++r) a4[r] = *(const float4*)&Ts[r * DIM + d];
        #pragma unroll
        for (int i = 0; i < 4; ++i) {
            #pragma unroll
            for (int r = 0; r < 8; ++r)
                acc[i][r] += xcur[i].x * a4[r].x + xcur[i].y * a4[r].y +
                             xcur[i].z * a4[r].z + xcur[i].w * a4[r].w;
        }
        #pragma unroll
        for (int i = 0; i < 4; ++i) xcur[i] = xnxt[i];
    }

    // butterfly reduce across 64 lanes -> every lane holds xa[i][r]
    float xa[4][8];
    #pragma unroll
    for (int i = 0; i < 4; ++i) {
        #pragma unroll
        for (int r = 0; r < 8; ++r) {
            float v = acc[i][r];
            #pragma unroll
            for (int off = 32; off; off >>= 1) v += __shfl_xor(v, off, 64);
            xa[i][r] = v;
        }
    }

    // ---- re-stage LDS with B[b] (SCALING already folded in) ----
    __syncthreads();   // everyone done reading A from Ts
    {
        const float4* __restrict__ src = (const float4*)(B + b * (RR * DIM));
        float4* dst = (float4*)Ts;
        for (int i = threadIdx.x; i < RR * DIM / 4; i += 512) dst[i] = src[i];
    }
    __syncthreads();

    // ---- phase 2: out = xa . B ----
    float* __restrict__ ob =
        out + ((size_t)b * SEQ + tile * 32 + wave * 4) * DIM;
    #pragma unroll
    for (int j = 0; j < 8; ++j) {
        const int o = j * 256 + lane * 4;
        float4 b4[8];
        #pragma unroll
        for (int r = 0; r < 8; ++r) b4[r] = *(const float4*)&Ts[r * DIM + o];
        #pragma unroll
        for (int i = 0; i < 4; ++i) {
            float4 v = {0.0f, 0.0f, 0.0f, 0.0f};
            #pragma unroll
            for (int r = 0; r < 8; ++r) {
                v.x += xa[i][r] * b4[r].x;
                v.y += xa[i][r] * b4[r].y;
                v.z += xa[i][r] * b4[r].z;
                v.w += xa[i][r] * b4[r].w;
            }
            *(float4*)&ob[(size_t)i * DIM + o] = v;
        }
    }
}

extern "C" void kernel_launch(void* const* d_in, const int* in_sizes, int n_in,
                              void* d_out, int out_size, void* d_ws, size_t ws_size,
                              hipStream_t stream) {
    const float* x     = (const float*)d_in[0];
    const float* ctr   = (const float*)d_in[1];
    const float* gamma = (const float*)d_in[2];
    const float* beta  = (const float*)d_in[3];
    const float* W1    = (const float*)d_in[4];
    const float* b1    = (const float*)d_in[5];
    const float* W2    = (const float*)d_in[6];
    const float* b2    = (const float*)d_in[7];
    const float* Wa    = (const float*)d_in[8];
    const float* Wb    = (const float*)d_in[9];

    float* ws = (float*)d_ws;
    float* A  = ws;                  // 131072 floats
    float* B  = ws + 131072;         // 131072 floats
    float* out = (float*)d_out;

    gate_ab_kernel<<<128, 256, 0, stream>>>(ctr, gamma, beta, W1, b1, W2, b2,
                                            Wa, Wb, A, B);
    fused_kernel<<<BS * 64, 512, 0, stream>>>(x, A, B, out);
}